// Round 1
// baseline (1053.967 us; speedup 1.0000x reference)
//
#include <hip/hip_runtime.h>

#define N_NODES 100000
#define N_HEDGES 100000
#define N_INC 1600000
#define D 128

// ---------------- degree histogram ----------------
__global__ void degree_kernel(const int* __restrict__ nidx, const int* __restrict__ hidx,
                              int* __restrict__ cnt_n, int* __restrict__ cnt_e) {
    int i = blockIdx.x * blockDim.x + threadIdx.x;
    if (i < N_INC) {
        atomicAdd(&cnt_n[nidx[i]], 1);
        atomicAdd(&cnt_e[hidx[i]], 1);
    }
}

__global__ void recip_kernel(const int* __restrict__ cn, const int* __restrict__ ce,
                             float* __restrict__ dinv, float* __restrict__ binv) {
    int i = blockIdx.x * blockDim.x + threadIdx.x;
    if (i < N_NODES) {
        dinv[i] = cn[i] > 0 ? 1.0f / (float)cn[i] : 0.0f;
        binv[i] = ce[i] > 0 ? 1.0f / (float)ce[i] : 0.0f;
    }
}

// ---------------- exclusive scan (3 kernels) ----------------
__global__ void scan_block_kernel(const int* __restrict__ in, int* __restrict__ tmp,
                                  int* __restrict__ bsums, int n) {
    __shared__ int s[1024];
    int i = blockIdx.x * 1024 + threadIdx.x;
    int v = (i < n) ? in[i] : 0;
    s[threadIdx.x] = v;
    __syncthreads();
    for (int off = 1; off < 1024; off <<= 1) {
        int t = 0;
        if ((int)threadIdx.x >= off) t = s[threadIdx.x - off];
        __syncthreads();
        s[threadIdx.x] += t;
        __syncthreads();
    }
    if (i < n) tmp[i] = s[threadIdx.x];
    if (threadIdx.x == 1023) bsums[blockIdx.x] = s[1023];
}

__global__ void scan_sums_kernel(int* __restrict__ bsums, int nb) {
    if (threadIdx.x == 0 && blockIdx.x == 0) {
        int run = 0;
        for (int i = 0; i < nb; ++i) { run += bsums[i]; bsums[i] = run; }
    }
}

__global__ void scan_finalize_kernel(const int* __restrict__ in, const int* __restrict__ tmp,
                                     const int* __restrict__ bsums, int* __restrict__ rowptr,
                                     int n, int nb) {
    int i = blockIdx.x * 1024 + threadIdx.x;
    if (i < n) {
        int off = (blockIdx.x > 0) ? bsums[blockIdx.x - 1] : 0;
        rowptr[i] = tmp[i] - in[i] + off;
        if (i == n - 1) rowptr[n] = bsums[nb - 1];
    }
}

// ---------------- CSR fill ----------------
__global__ void fill_kernel(const int* __restrict__ nidx, const int* __restrict__ hidx,
                            const int* __restrict__ rp_n, const int* __restrict__ rp_e,
                            int* __restrict__ fill_n, int* __restrict__ fill_e,
                            int* __restrict__ csr_n, int* __restrict__ csr_e) {
    int i = blockIdx.x * blockDim.x + threadIdx.x;
    if (i < N_INC) {
        int n = nidx[i], h = hidx[i];
        int pn = rp_n[n] + atomicAdd(&fill_n[n], 1);
        csr_n[pn] = h;   // per node: list of incident hyperedges
        int pe = rp_e[h] + atomicAdd(&fill_e[h], 1);
        csr_e[pe] = n;   // per hedge: list of member nodes
    }
}

// ---------------- f32 GEMM: Y[nrows,128] = X[nrows,128] * W[128,128] ----------------
__launch_bounds__(256)
__global__ void gemm128_kernel(const float* __restrict__ X, const float* __restrict__ W,
                               float* __restrict__ Y, int nrows) {
    __shared__ float xs[64 * 128];   // 32 KiB
    int tid = threadIdx.x;
    int row0 = blockIdx.x * 64;
    const float4* xg = (const float4*)X;
    float4* xs4 = (float4*)xs;
#pragma unroll
    for (int i = 0; i < 8; ++i) {
        int f4 = tid + i * 256;              // 0..2047 (64 rows x 32 float4)
        int row = row0 + (f4 >> 5);
        float4 v = make_float4(0.f, 0.f, 0.f, 0.f);
        if (row < nrows) v = xg[(size_t)row * 32 + (f4 & 31)];
        xs4[f4] = v;
    }
    __syncthreads();

    int cg = tid & 31;        // 32 column groups of 4
    int rg = tid >> 5;        // 8 row groups of 8
    int c0 = cg * 4;
    float acc[8][4];
#pragma unroll
    for (int r = 0; r < 8; ++r)
#pragma unroll
        for (int c = 0; c < 4; ++c) acc[r][c] = 0.f;

    for (int k0 = 0; k0 < 128; k0 += 4) {
        float4 w0 = *(const float4*)(W + (size_t)(k0 + 0) * 128 + c0);
        float4 w1 = *(const float4*)(W + (size_t)(k0 + 1) * 128 + c0);
        float4 w2 = *(const float4*)(W + (size_t)(k0 + 2) * 128 + c0);
        float4 w3 = *(const float4*)(W + (size_t)(k0 + 3) * 128 + c0);
#pragma unroll
        for (int r = 0; r < 8; ++r) {
            float4 xv = *(const float4*)(xs + (rg * 8 + r) * 128 + k0);
            acc[r][0] += xv.x * w0.x + xv.y * w1.x + xv.z * w2.x + xv.w * w3.x;
            acc[r][1] += xv.x * w0.y + xv.y * w1.y + xv.z * w2.y + xv.w * w3.y;
            acc[r][2] += xv.x * w0.z + xv.y * w1.z + xv.z * w2.z + xv.w * w3.z;
            acc[r][3] += xv.x * w0.w + xv.y * w1.w + xv.z * w2.w + xv.w * w3.w;
        }
    }
#pragma unroll
    for (int r = 0; r < 8; ++r) {
        int row = row0 + rg * 8 + r;
        if (row < nrows)
            *(float4*)(Y + (size_t)row * 128 + c0) =
                make_float4(acc[r][0], acc[r][1], acc[r][2], acc[r][3]);
    }
}

// ---------------- segment gather-sum helpers ----------------
// one 64-lane wave per segment; lane owns features {2*lane, 2*lane+1}
__device__ __forceinline__ void seg_sum_f2(const float* __restrict__ src,
                                           const int* __restrict__ col,
                                           int s, int e, int lane,
                                           float& ax, float& ay) {
    ax = 0.f; ay = 0.f;
    for (int base = s; base < e; base += 64) {
        int j = base + lane;
        int myidx = (j < e) ? col[j] : 0;
        int cnt = e - base; if (cnt > 64) cnt = 64;
        int m = 0;
        for (; m + 4 <= cnt; m += 4) {
            int i0 = __shfl(myidx, m);
            int i1 = __shfl(myidx, m + 1);
            int i2 = __shfl(myidx, m + 2);
            int i3 = __shfl(myidx, m + 3);
            float2 v0 = *(const float2*)(src + (size_t)i0 * D + lane * 2);
            float2 v1 = *(const float2*)(src + (size_t)i1 * D + lane * 2);
            float2 v2 = *(const float2*)(src + (size_t)i2 * D + lane * 2);
            float2 v3 = *(const float2*)(src + (size_t)i3 * D + lane * 2);
            ax += v0.x + v1.x + v2.x + v3.x;
            ay += v0.y + v1.y + v2.y + v3.y;
        }
        for (; m < cnt; ++m) {
            int i0 = __shfl(myidx, m);
            float2 v = *(const float2*)(src + (size_t)i0 * D + lane * 2);
            ax += v.x; ay += v.y;
        }
    }
}

// e[h] = Binv[h] * sum_{nodes in h} src[node]
__launch_bounds__(256)
__global__ void edge_agg_kernel(const float* __restrict__ src, const int* __restrict__ rowptr,
                                const int* __restrict__ col, const float* __restrict__ scale,
                                float* __restrict__ dst) {
    int wid = threadIdx.x >> 6, lane = threadIdx.x & 63;
    int seg = blockIdx.x * 4 + wid;
    int s = rowptr[seg], e = rowptr[seg + 1];
    float ax, ay;
    seg_sum_f2(src, col, s, e, lane, ax, ay);
    float sc = scale[seg];
    float2 o; o.x = ax * sc; o.y = ay * sc;
    *(float2*)(dst + (size_t)seg * D + lane * 2) = o;
}

// out[n] = relu(Dinv[n] * sum_{hedges at n} src[hedge] + bias)
__launch_bounds__(256)
__global__ void node_agg_relu_kernel(const float* __restrict__ src, const int* __restrict__ rowptr,
                                     const int* __restrict__ col, const float* __restrict__ scale,
                                     const float* __restrict__ bias, float* __restrict__ dst) {
    int wid = threadIdx.x >> 6, lane = threadIdx.x & 63;
    int seg = blockIdx.x * 4 + wid;
    int s = rowptr[seg], e = rowptr[seg + 1];
    float ax, ay;
    seg_sum_f2(src, col, s, e, lane, ax, ay);
    float sc = scale[seg];
    float2 b = *(const float2*)(bias + lane * 2);
    float2 o;
    o.x = fmaxf(ax * sc + b.x, 0.f);
    o.y = fmaxf(ay * sc + b.y, 0.f);
    *(float2*)(dst + (size_t)seg * D + lane * 2) = o;
}

// final layer: relu node output, reduced to per-block partial column sums
__launch_bounds__(256)
__global__ void node_agg_final_kernel(const float* __restrict__ src, const int* __restrict__ rowptr,
                                      const int* __restrict__ col, const float* __restrict__ scale,
                                      const float* __restrict__ bias, float* __restrict__ partials) {
    __shared__ float sd[4 * 128];
    int wid = threadIdx.x >> 6, lane = threadIdx.x & 63;
    int seg = blockIdx.x * 4 + wid;
    int s = rowptr[seg], e = rowptr[seg + 1];
    float ax, ay;
    seg_sum_f2(src, col, s, e, lane, ax, ay);
    float sc = scale[seg];
    float2 b = *(const float2*)(bias + lane * 2);
    float ox = fmaxf(ax * sc + b.x, 0.f);
    float oy = fmaxf(ay * sc + b.y, 0.f);
    sd[wid * 128 + lane * 2] = ox;
    sd[wid * 128 + lane * 2 + 1] = oy;
    __syncthreads();
    int t = threadIdx.x;
    if (t < 128) {
        partials[(size_t)blockIdx.x * 128 + t] =
            sd[t] + sd[128 + t] + sd[256 + t] + sd[384 + t];
    }
}

__global__ void mean_reduce_kernel(const float* __restrict__ partials, float* __restrict__ out,
                                   int nblocks) {
    __shared__ float sd[256];
    int c = blockIdx.x;
    float acc = 0.f;
    for (int i = threadIdx.x; i < nblocks; i += 256)
        acc += partials[(size_t)i * 128 + c];
    sd[threadIdx.x] = acc;
    __syncthreads();
    for (int off = 128; off > 0; off >>= 1) {
        if ((int)threadIdx.x < off) sd[threadIdx.x] += sd[threadIdx.x + off];
        __syncthreads();
    }
    if (threadIdx.x == 0) out[c] = sd[0] * (1.0f / (float)N_NODES);
}

// ---------------- launch ----------------
extern "C" void kernel_launch(void* const* d_in, const int* in_sizes, int n_in,
                              void* d_out, int out_size, void* d_ws, size_t ws_size,
                              hipStream_t stream) {
    const float* x  = (const float*)d_in[0];
    const int*   ei = (const int*)d_in[1];
    const float* w1 = (const float*)d_in[2];
    const float* b1 = (const float*)d_in[3];
    const float* w2 = (const float*)d_in[4];
    const float* b2 = (const float*)d_in[5];
    float* out = (float*)d_out;
    const int* nidx = ei;
    const int* hidx = ei + N_INC;

    char* wsp = (char*)d_ws;
    size_t off = 0;
    auto alloc = [&](size_t bytes) -> void* {
        void* p = wsp + off;
        off += (bytes + 255) & ~(size_t)255;
        return p;
    };

    float* B0       = (float*)alloc((size_t)N_NODES * 128 * 4);
    float* B1       = (float*)alloc((size_t)N_NODES * 128 * 4);
    int*   csr_e    = (int*)alloc((size_t)N_INC * 4);
    int*   csr_n    = (int*)alloc((size_t)N_INC * 4);
    float* partials = (float*)alloc((size_t)(N_NODES / 4) * 128 * 4);
    int*   rp_n     = (int*)alloc((size_t)(N_NODES + 1) * 4);
    int*   rp_e     = (int*)alloc((size_t)(N_HEDGES + 1) * 4);
    int*   tmp      = (int*)alloc((size_t)N_NODES * 4);
    int*   bsums    = (int*)alloc(1024 * 4);
    float* dinv     = (float*)alloc((size_t)N_NODES * 4);
    float* binv     = (float*)alloc((size_t)N_HEDGES * 4);
    int*   zeros    = (int*)alloc((size_t)4 * N_NODES * 4);
    int* cnt_n  = zeros;
    int* cnt_e  = zeros + N_NODES;
    int* fill_n = zeros + 2 * N_NODES;
    int* fill_e = zeros + 3 * N_NODES;

    hipMemsetAsync(zeros, 0, (size_t)4 * N_NODES * sizeof(int), stream);

    int gInc = (N_INC + 255) / 256;
    degree_kernel<<<gInc, 256, 0, stream>>>(nidx, hidx, cnt_n, cnt_e);
    recip_kernel<<<(N_NODES + 255) / 256, 256, 0, stream>>>(cnt_n, cnt_e, dinv, binv);

    int nb = (N_NODES + 1023) / 1024;
    scan_block_kernel<<<nb, 1024, 0, stream>>>(cnt_n, tmp, bsums, N_NODES);
    scan_sums_kernel<<<1, 64, 0, stream>>>(bsums, nb);
    scan_finalize_kernel<<<nb, 1024, 0, stream>>>(cnt_n, tmp, bsums, rp_n, N_NODES, nb);
    scan_block_kernel<<<nb, 1024, 0, stream>>>(cnt_e, tmp, bsums, N_NODES);
    scan_sums_kernel<<<1, 64, 0, stream>>>(bsums, nb);
    scan_finalize_kernel<<<nb, 1024, 0, stream>>>(cnt_e, tmp, bsums, rp_e, N_NODES, nb);

    fill_kernel<<<gInc, 256, 0, stream>>>(nidx, hidx, rp_n, rp_e, fill_n, fill_e, csr_n, csr_e);

    int gGemm = (N_NODES + 63) / 64;
    int gSeg = N_NODES / 4;   // 25000 blocks, 4 waves each

    // layer 1
    gemm128_kernel<<<gGemm, 256, 0, stream>>>(x, w1, B0, N_NODES);
    edge_agg_kernel<<<gSeg, 256, 0, stream>>>(B0, rp_e, csr_e, binv, B1);
    node_agg_relu_kernel<<<gSeg, 256, 0, stream>>>(B1, rp_n, csr_n, dinv, b1, B0);
    // layer 2
    gemm128_kernel<<<gGemm, 256, 0, stream>>>(B0, w2, B1, N_NODES);
    edge_agg_kernel<<<gSeg, 256, 0, stream>>>(B1, rp_e, csr_e, binv, B0);
    node_agg_final_kernel<<<gSeg, 256, 0, stream>>>(B0, rp_n, csr_n, dinv, b2, partials);
    mean_reduce_kernel<<<128, 256, 0, stream>>>(partials, out, N_NODES / 4);
}

// Round 3
// 551.435 us; speedup vs baseline: 1.9113x; 1.9113x over previous
//
#include <hip/hip_runtime.h>
#include <hip/hip_bf16.h>

#define N_NODES 100000
#define N_HEDGES 100000
#define N_INC 1600000
#define D 128

#define B_KEYS 512            // keys per bucket
#define NBUCK 196             // ceil(100000/512)
#define CAP 10240             // bucket capacity (mean 8192, sigma ~90 -> 22 sigma margin)
#define NBLKA 200
#define CHUNK (N_INC / NBLKA) // 8000

// ---------------- Phase A: bucket partition both directions ----------------
__launch_bounds__(256)
__global__ void binA_kernel(const int* __restrict__ nidx, const int* __restrict__ hidx,
                            int* __restrict__ gcnt_e, int* __restrict__ gcnt_n,
                            unsigned* __restrict__ bin_e, unsigned* __restrict__ bin_n) {
    __shared__ int hist_e[NBUCK], hist_n[NBUCK], base_e[NBUCK], base_n[NBUCK];
    int t = threadIdx.x;
    for (int b = t; b < NBUCK; b += 256) { hist_e[b] = 0; hist_n[b] = 0; }
    __syncthreads();
    int start = blockIdx.x * CHUNK;
    for (int i = t; i < CHUNK; i += 256) {
        int h = hidx[start + i], n = nidx[start + i];
        atomicAdd(&hist_e[h >> 9], 1);
        atomicAdd(&hist_n[n >> 9], 1);
    }
    __syncthreads();
    for (int b = t; b < NBUCK; b += 256) {
        base_e[b] = atomicAdd(&gcnt_e[b], hist_e[b]);
        base_n[b] = atomicAdd(&gcnt_n[b], hist_n[b]);
        hist_e[b] = 0; hist_n[b] = 0;
    }
    __syncthreads();
    for (int i = t; i < CHUNK; i += 256) {
        int h = hidx[start + i], n = nidx[start + i];
        int be = h >> 9, bn = n >> 9;
        int oe = base_e[be] + atomicAdd(&hist_e[be], 1);
        if (oe >= 0 && oe < CAP) bin_e[(size_t)be * CAP + oe] = ((unsigned)(h & 511) << 17) | (unsigned)n;
        int on = base_n[bn] + atomicAdd(&hist_n[bn], 1);
        if (on >= 0 && on < CAP) bin_n[(size_t)bn * CAP + on] = ((unsigned)(n & 511) << 17) | (unsigned)h;
    }
}

// ---------------- Phase B: per-bucket counting sort -> csr + seg meta ----------------
__launch_bounds__(512)
__global__ void binB_kernel(const int* __restrict__ gcnt, const unsigned* __restrict__ bin,
                            int* __restrict__ csr, int* __restrict__ seg_start,
                            int* __restrict__ seg_cnt, float* __restrict__ scale) {
    __shared__ int kc[B_KEYS];   // per-key count, then fill cursor
    __shared__ int ks[B_KEYS];   // scan
    int b = blockIdx.x;
    int t = threadIdx.x;
    int cnt = gcnt[b];
    if (cnt > CAP) cnt = CAP;
    kc[t] = 0;
    __syncthreads();
    const unsigned* items = bin + (size_t)b * CAP;
    for (int i = t; i < cnt; i += 512) atomicAdd(&kc[items[i] >> 17], 1);
    __syncthreads();
    ks[t] = kc[t];
    __syncthreads();
    for (int off = 1; off < 512; off <<= 1) {
        int v = (t >= off) ? ks[t - off] : 0;
        __syncthreads();
        ks[t] += v;
        __syncthreads();
    }
    int mycnt = kc[t];
    int sstart = b * CAP + (ks[t] - mycnt);   // exclusive scan start
    int k = b * B_KEYS + t;
    if (k < N_NODES) {
        seg_start[k] = sstart;
        seg_cnt[k] = mycnt;
        scale[k] = mycnt ? 1.0f / (float)mycnt : 0.0f;
    }
    __syncthreads();
    kc[t] = sstart;   // becomes fill cursor
    __syncthreads();
    for (int i = t; i < cnt; i += 512) {
        unsigned it = items[i];
        int pos = atomicAdd(&kc[it >> 17], 1);
        csr[pos] = (int)(it & 0x1FFFFu);
    }
}

// ---------------- GEMM: Y[nrows,128](bf16) = X[nrows,128] * W[128,128] (f32 math) ----
template <typename T>
__launch_bounds__(256)
__global__ void gemm128_kernel(const T* __restrict__ X, const float* __restrict__ W,
                               __hip_bfloat16* __restrict__ Y, int nrows) {
    __shared__ float xs[64 * 128];   // 32 KiB
    int tid = threadIdx.x;
    int row0 = blockIdx.x * 64;

    if constexpr (sizeof(T) == 4) {
        const float4* xg = (const float4*)X;
        float4* xs4 = (float4*)xs;
#pragma unroll
        for (int i = 0; i < 8; ++i) {
            int f4 = tid + i * 256;              // 64 rows x 32 float4
            int row = row0 + (f4 >> 5);
            float4 v = make_float4(0.f, 0.f, 0.f, 0.f);
            if (row < nrows) v = xg[(size_t)row * 32 + (f4 & 31)];
            xs4[f4] = v;
        }
    } else {
        // bf16 input: 64 rows x 16 chunks of 8 bf16 (16B)
#pragma unroll
        for (int i = 0; i < 4; ++i) {
            int c = tid + i * 256;               // 0..1023
            int row = row0 + (c >> 4);
            int g = c & 15;
            uint4 u = make_uint4(0, 0, 0, 0);
            if (row < nrows) u = *(const uint4*)((const char*)X + (size_t)row * 256 + g * 16);
            float* d = xs + (c >> 4) * 128 + g * 8;
            d[0] = __uint_as_float(u.x << 16); d[1] = __uint_as_float(u.x & 0xFFFF0000u);
            d[2] = __uint_as_float(u.y << 16); d[3] = __uint_as_float(u.y & 0xFFFF0000u);
            d[4] = __uint_as_float(u.z << 16); d[5] = __uint_as_float(u.z & 0xFFFF0000u);
            d[6] = __uint_as_float(u.w << 16); d[7] = __uint_as_float(u.w & 0xFFFF0000u);
        }
    }
    __syncthreads();

    int cg = tid & 31;        // 32 column groups of 4
    int rg = tid >> 5;        // 8 row groups of 8
    int c0 = cg * 4;
    float acc[8][4];
#pragma unroll
    for (int r = 0; r < 8; ++r)
#pragma unroll
        for (int c = 0; c < 4; ++c) acc[r][c] = 0.f;

    for (int k0 = 0; k0 < 128; k0 += 4) {
        float4 w0 = *(const float4*)(W + (size_t)(k0 + 0) * 128 + c0);
        float4 w1 = *(const float4*)(W + (size_t)(k0 + 1) * 128 + c0);
        float4 w2 = *(const float4*)(W + (size_t)(k0 + 2) * 128 + c0);
        float4 w3 = *(const float4*)(W + (size_t)(k0 + 3) * 128 + c0);
#pragma unroll
        for (int r = 0; r < 8; ++r) {
            float4 xv = *(const float4*)(xs + (rg * 8 + r) * 128 + k0);
            acc[r][0] += xv.x * w0.x + xv.y * w1.x + xv.z * w2.x + xv.w * w3.x;
            acc[r][1] += xv.x * w0.y + xv.y * w1.y + xv.z * w2.y + xv.w * w3.y;
            acc[r][2] += xv.x * w0.z + xv.y * w1.z + xv.z * w2.z + xv.w * w3.z;
            acc[r][3] += xv.x * w0.w + xv.y * w1.w + xv.z * w2.w + xv.w * w3.w;
        }
    }
#pragma unroll
    for (int r = 0; r < 8; ++r) {
        int row = row0 + rg * 8 + r;
        if (row < nrows) {
            __hip_bfloat162 p0 = __float22bfloat162_rn(make_float2(acc[r][0], acc[r][1]));
            __hip_bfloat162 p1 = __float22bfloat162_rn(make_float2(acc[r][2], acc[r][3]));
            uint2 pk;
            pk.x = *(unsigned*)&p0;
            pk.y = *(unsigned*)&p1;
            *(uint2*)((char*)Y + (size_t)row * 256 + c0 * 2) = pk;
        }
    }
}

// ---------------- segment gather-sum (bf16 tables, f32 accumulate) ----------------
// one 64-lane wave per segment; lane owns features {2*lane, 2*lane+1}
__device__ __forceinline__ void seg_sum_bf2(const __hip_bfloat162* __restrict__ src,
                                            const int* __restrict__ col,
                                            int s, int e, int lane,
                                            float& ax, float& ay) {
    ax = 0.f; ay = 0.f;
    for (int base = s; base < e; base += 64) {
        int j = base + lane;
        int myidx = (j < e) ? col[j] : 0;
        int cnt = e - base; if (cnt > 64) cnt = 64;
        int m = 0;
        for (; m + 4 <= cnt; m += 4) {
            int i0 = __shfl(myidx, m);
            int i1 = __shfl(myidx, m + 1);
            int i2 = __shfl(myidx, m + 2);
            int i3 = __shfl(myidx, m + 3);
            float2 v0 = __bfloat1622float2(src[(size_t)i0 * 64 + lane]);
            float2 v1 = __bfloat1622float2(src[(size_t)i1 * 64 + lane]);
            float2 v2 = __bfloat1622float2(src[(size_t)i2 * 64 + lane]);
            float2 v3 = __bfloat1622float2(src[(size_t)i3 * 64 + lane]);
            ax += v0.x + v1.x + v2.x + v3.x;
            ay += v0.y + v1.y + v2.y + v3.y;
        }
        for (; m < cnt; ++m) {
            int i0 = __shfl(myidx, m);
            float2 v = __bfloat1622float2(src[(size_t)i0 * 64 + lane]);
            ax += v.x; ay += v.y;
        }
    }
}

// e[h] = Binv[h] * sum_{nodes in h} src[node]     (bf16 out)
__launch_bounds__(256)
__global__ void edge_agg_kernel(const __hip_bfloat162* __restrict__ src,
                                const int* __restrict__ seg_start, const int* __restrict__ seg_cnt,
                                const int* __restrict__ col, const float* __restrict__ scale,
                                __hip_bfloat162* __restrict__ dst) {
    int wid = threadIdx.x >> 6, lane = threadIdx.x & 63;
    int seg = blockIdx.x * 4 + wid;
    int s = seg_start[seg], e = s + seg_cnt[seg];
    float ax, ay;
    seg_sum_bf2(src, col, s, e, lane, ax, ay);
    float sc = scale[seg];
    dst[(size_t)seg * 64 + lane] = __float22bfloat162_rn(make_float2(ax * sc, ay * sc));
}

// out[n] = relu(Dinv[n] * sum + bias)   (bf16 out)
__launch_bounds__(256)
__global__ void node_agg_relu_kernel(const __hip_bfloat162* __restrict__ src,
                                     const int* __restrict__ seg_start, const int* __restrict__ seg_cnt,
                                     const int* __restrict__ col, const float* __restrict__ scale,
                                     const float* __restrict__ bias,
                                     __hip_bfloat162* __restrict__ dst) {
    int wid = threadIdx.x >> 6, lane = threadIdx.x & 63;
    int seg = blockIdx.x * 4 + wid;
    int s = seg_start[seg], e = s + seg_cnt[seg];
    float ax, ay;
    seg_sum_bf2(src, col, s, e, lane, ax, ay);
    float sc = scale[seg];
    float2 b = *(const float2*)(bias + lane * 2);
    float ox = fmaxf(ax * sc + b.x, 0.f);
    float oy = fmaxf(ay * sc + b.y, 0.f);
    dst[(size_t)seg * 64 + lane] = __float22bfloat162_rn(make_float2(ox, oy));
}

// final layer: relu node output -> per-block partial column sums (f32)
__launch_bounds__(256)
__global__ void node_agg_final_kernel(const __hip_bfloat162* __restrict__ src,
                                      const int* __restrict__ seg_start, const int* __restrict__ seg_cnt,
                                      const int* __restrict__ col, const float* __restrict__ scale,
                                      const float* __restrict__ bias,
                                      float* __restrict__ partials) {
    __shared__ float sd[4 * 128];
    int wid = threadIdx.x >> 6, lane = threadIdx.x & 63;
    int seg = blockIdx.x * 4 + wid;
    int s = seg_start[seg], e = s + seg_cnt[seg];
    float ax, ay;
    seg_sum_bf2(src, col, s, e, lane, ax, ay);
    float sc = scale[seg];
    float2 b = *(const float2*)(bias + lane * 2);
    sd[wid * 128 + lane * 2]     = fmaxf(ax * sc + b.x, 0.f);
    sd[wid * 128 + lane * 2 + 1] = fmaxf(ay * sc + b.y, 0.f);
    __syncthreads();
    int t = threadIdx.x;
    if (t < 128) {
        partials[(size_t)blockIdx.x * 128 + t] =
            sd[t] + sd[128 + t] + sd[256 + t] + sd[384 + t];
    }
}

__global__ void mean_reduce_kernel(const float* __restrict__ partials, float* __restrict__ out,
                                   int nblocks) {
    __shared__ float sd[256];
    int c = blockIdx.x;
    float acc = 0.f;
    for (int i = threadIdx.x; i < nblocks; i += 256)
        acc += partials[(size_t)i * 128 + c];
    sd[threadIdx.x] = acc;
    __syncthreads();
    for (int off = 128; off > 0; off >>= 1) {
        if ((int)threadIdx.x < off) sd[threadIdx.x] += sd[threadIdx.x + off];
        __syncthreads();
    }
    if (threadIdx.x == 0) out[c] = sd[0] * (1.0f / (float)N_NODES);
}

// ---------------- launch ----------------
extern "C" void kernel_launch(void* const* d_in, const int* in_sizes, int n_in,
                              void* d_out, int out_size, void* d_ws, size_t ws_size,
                              hipStream_t stream) {
    const float* x  = (const float*)d_in[0];
    const int*   ei = (const int*)d_in[1];
    const float* w1 = (const float*)d_in[2];
    const float* b1 = (const float*)d_in[3];
    const float* w2 = (const float*)d_in[4];
    const float* b2 = (const float*)d_in[5];
    float* out = (float*)d_out;
    const int* nidx = ei;
    const int* hidx = ei + N_INC;

    char* wsp = (char*)d_ws;
    size_t off = 0;
    auto alloc = [&](size_t bytes) -> void* {
        void* p = wsp + off;
        off += (bytes + 255) & ~(size_t)255;
        return p;
    };

    __hip_bfloat162* B0 = (__hip_bfloat162*)alloc((size_t)N_NODES * 128 * 2);
    __hip_bfloat162* B1 = (__hip_bfloat162*)alloc((size_t)N_NODES * 128 * 2);
    unsigned* bin_e  = (unsigned*)alloc((size_t)NBUCK * CAP * 4);
    unsigned* bin_n  = (unsigned*)alloc((size_t)NBUCK * CAP * 4);
    int* csr_e       = (int*)alloc((size_t)NBUCK * CAP * 4);
    int* csr_n       = (int*)alloc((size_t)NBUCK * CAP * 4);
    float* partials  = (float*)alloc((size_t)(N_NODES / 4) * 128 * 4);
    int* segs_e      = (int*)alloc((size_t)N_NODES * 4);
    int* segc_e      = (int*)alloc((size_t)N_NODES * 4);
    int* segs_n      = (int*)alloc((size_t)N_NODES * 4);
    int* segc_n      = (int*)alloc((size_t)N_NODES * 4);
    float* scale_e   = (float*)alloc((size_t)N_NODES * 4);
    float* scale_n   = (float*)alloc((size_t)N_NODES * 4);
    // single contiguous allocation for BOTH counter arrays so one memset
    // covers them exactly (alloc() rounds sizes up -> separate allocs left
    // gcnt_n partially poisoned in round 2: negative bases -> OOB writes)
    int* gcnt        = (int*)alloc((size_t)2 * NBUCK * 4);
    int* gcnt_e = gcnt;
    int* gcnt_n = gcnt + NBUCK;

    hipMemsetAsync(gcnt, 0, (size_t)2 * NBUCK * sizeof(int), stream);

    binA_kernel<<<NBLKA, 256, 0, stream>>>(nidx, hidx, gcnt_e, gcnt_n, bin_e, bin_n);
    binB_kernel<<<NBUCK, 512, 0, stream>>>(gcnt_e, bin_e, csr_e, segs_e, segc_e, scale_e);
    binB_kernel<<<NBUCK, 512, 0, stream>>>(gcnt_n, bin_n, csr_n, segs_n, segc_n, scale_n);

    int gGemm = (N_NODES + 63) / 64;
    int gSeg = N_NODES / 4;

    // layer 1
    gemm128_kernel<float><<<gGemm, 256, 0, stream>>>(x, w1, (__hip_bfloat16*)B0, N_NODES);
    edge_agg_kernel<<<gSeg, 256, 0, stream>>>(B0, segs_e, segc_e, csr_e, scale_e, B1);
    node_agg_relu_kernel<<<gSeg, 256, 0, stream>>>(B1, segs_n, segc_n, csr_n, scale_n, b1, B0);
    // layer 2
    gemm128_kernel<__hip_bfloat16><<<gGemm, 256, 0, stream>>>((const __hip_bfloat16*)B0, w2,
                                                              (__hip_bfloat16*)B1, N_NODES);
    edge_agg_kernel<<<gSeg, 256, 0, stream>>>(B1, segs_e, segc_e, csr_e, scale_e, B0);
    node_agg_final_kernel<<<gSeg, 256, 0, stream>>>(B0, segs_n, segc_n, csr_n, scale_n, b2, partials);
    mean_reduce_kernel<<<128, 256, 0, stream>>>(partials, out, N_NODES / 4);
}

// Round 4
// 501.670 us; speedup vs baseline: 2.1009x; 1.0992x over previous
//
#include <hip/hip_runtime.h>
#include <hip/hip_bf16.h>

#define N_NODES 100000
#define N_HEDGES 100000
#define N_INC 1600000
#define D 128

#define B_KEYS 512            // keys per bucket
#define NBUCK 196             // ceil(100000/512)
#define CAP 10240             // bucket capacity (mean 8192, sigma ~90)
#define NBLKA 200
#define CHUNK (N_INC / NBLKA) // 8000

#define LDA 136               // padded bf16 row stride for GEMM LDS tiles

typedef __attribute__((ext_vector_type(8))) short bf16x8;
typedef __attribute__((ext_vector_type(4))) float f32x4;

__device__ __forceinline__ short f2bf(float v) {
    __hip_bfloat16 b = __float2bfloat16(v);
    return *(short*)&b;
}

// ---------------- Phase A: bucket partition both directions ----------------
__launch_bounds__(256)
__global__ void binA_kernel(const int* __restrict__ nidx, const int* __restrict__ hidx,
                            int* __restrict__ gcnt_e, int* __restrict__ gcnt_n,
                            unsigned* __restrict__ bin_e, unsigned* __restrict__ bin_n) {
    __shared__ int hist_e[NBUCK], hist_n[NBUCK], base_e[NBUCK], base_n[NBUCK];
    int t = threadIdx.x;
    for (int b = t; b < NBUCK; b += 256) { hist_e[b] = 0; hist_n[b] = 0; }
    __syncthreads();
    int start = blockIdx.x * CHUNK;
    for (int i = t; i < CHUNK; i += 256) {
        int h = hidx[start + i], n = nidx[start + i];
        atomicAdd(&hist_e[h >> 9], 1);
        atomicAdd(&hist_n[n >> 9], 1);
    }
    __syncthreads();
    for (int b = t; b < NBUCK; b += 256) {
        base_e[b] = atomicAdd(&gcnt_e[b], hist_e[b]);
        base_n[b] = atomicAdd(&gcnt_n[b], hist_n[b]);
        hist_e[b] = 0; hist_n[b] = 0;
    }
    __syncthreads();
    for (int i = t; i < CHUNK; i += 256) {
        int h = hidx[start + i], n = nidx[start + i];
        int be = h >> 9, bn = n >> 9;
        int oe = base_e[be] + atomicAdd(&hist_e[be], 1);
        if (oe >= 0 && oe < CAP) bin_e[(size_t)be * CAP + oe] = ((unsigned)(h & 511) << 17) | (unsigned)n;
        int on = base_n[bn] + atomicAdd(&hist_n[bn], 1);
        if (on >= 0 && on < CAP) bin_n[(size_t)bn * CAP + on] = ((unsigned)(n & 511) << 17) | (unsigned)h;
    }
}

// ---------------- Phase B: per-bucket counting sort -> csr + seg meta ----------------
__launch_bounds__(512)
__global__ void binB_kernel(const int* __restrict__ gcnt, const unsigned* __restrict__ bin,
                            int* __restrict__ csr, int* __restrict__ seg_start,
                            int* __restrict__ seg_cnt, float* __restrict__ scale) {
    __shared__ int kc[B_KEYS];
    __shared__ int ks[B_KEYS];
    int b = blockIdx.x;
    int t = threadIdx.x;
    int cnt = gcnt[b];
    if (cnt > CAP) cnt = CAP;
    kc[t] = 0;
    __syncthreads();
    const unsigned* items = bin + (size_t)b * CAP;
    for (int i = t; i < cnt; i += 512) atomicAdd(&kc[items[i] >> 17], 1);
    __syncthreads();
    ks[t] = kc[t];
    __syncthreads();
    for (int off = 1; off < 512; off <<= 1) {
        int v = (t >= off) ? ks[t - off] : 0;
        __syncthreads();
        ks[t] += v;
        __syncthreads();
    }
    int mycnt = kc[t];
    int sstart = b * CAP + (ks[t] - mycnt);
    int k = b * B_KEYS + t;
    if (k < N_NODES) {
        seg_start[k] = sstart;
        seg_cnt[k] = mycnt;
        scale[k] = mycnt ? 1.0f / (float)mycnt : 0.0f;
    }
    __syncthreads();
    kc[t] = sstart;
    __syncthreads();
    for (int i = t; i < cnt; i += 512) {
        unsigned it = items[i];
        int pos = atomicAdd(&kc[it >> 17], 1);
        csr[pos] = (int)(it & 0x1FFFFu);
    }
}

// ---------------- MFMA bf16 GEMM: Y[nrows,128](bf16) = X[nrows,128] * W[128,128] ----
// per block: 64 rows. LDS: A-tile 64x128 bf16 (stride LDA), W^T 128x128 bf16.
// wave w computes rows [w*16, w*16+16) x all 128 cols via 8 col-tiles x 4 k-steps.
template <typename T>
__launch_bounds__(256)
__global__ void gemm_mfma_kernel(const T* __restrict__ X, const float* __restrict__ W,
                                 __hip_bfloat16* __restrict__ Y, int nrows) {
    __shared__ short lds_a[64 * LDA];    // A tile, reused for output staging
    __shared__ short lds_w[128 * LDA];   // W^T: [n][k]
    int tid = threadIdx.x;
    int row0 = blockIdx.x * 64;

    // stage W^T: W[k][n] f32 -> lds_w[n*LDA + k]
    {
        const float4* w4 = (const float4*)W;
#pragma unroll
        for (int i = 0; i < 16; ++i) {
            int idx = tid + i * 256;          // k*32 + c4, 0..4095
            int k = idx >> 5;
            int n0 = (idx & 31) * 4;
            float4 v = w4[idx];
            lds_w[(n0 + 0) * LDA + k] = f2bf(v.x);
            lds_w[(n0 + 1) * LDA + k] = f2bf(v.y);
            lds_w[(n0 + 2) * LDA + k] = f2bf(v.z);
            lds_w[(n0 + 3) * LDA + k] = f2bf(v.w);
        }
    }
    // stage A tile as bf16
    if constexpr (sizeof(T) == 4) {
        const float4* xg = (const float4*)X;
#pragma unroll
        for (int i = 0; i < 8; ++i) {
            int f4 = tid + i * 256;           // 64 rows x 32 float4
            int row = f4 >> 5, c4 = f4 & 31;
            float4 v = make_float4(0.f, 0.f, 0.f, 0.f);
            if (row0 + row < nrows) v = xg[(size_t)(row0 + row) * 32 + c4];
            short* d = lds_a + row * LDA + c4 * 4;
            d[0] = f2bf(v.x); d[1] = f2bf(v.y); d[2] = f2bf(v.z); d[3] = f2bf(v.w);
        }
    } else {
#pragma unroll
        for (int i = 0; i < 4; ++i) {
            int c = tid + i * 256;            // 64 rows x 16 uint4
            int row = c >> 4, g = c & 15;
            uint4 u = make_uint4(0, 0, 0, 0);
            if (row0 + row < nrows) u = *(const uint4*)((const char*)X + (size_t)(row0 + row) * 256 + g * 16);
            *(uint4*)(lds_a + row * LDA + g * 8) = u;
        }
    }
    __syncthreads();

    int wv = tid >> 6, lane = tid & 63;
    int m = lane & 15, quad = lane >> 4;

    // A fragments: A[m][k = k0 + quad*8 + j]
    const short* arow = lds_a + (wv * 16 + m) * LDA + quad * 8;
    bf16x8 af[4];
#pragma unroll
    for (int k0 = 0; k0 < 4; ++k0) af[k0] = *(const bf16x8*)(arow + k0 * 32);

    f32x4 zero = {0.f, 0.f, 0.f, 0.f};
    f32x4 acc[8];
#pragma unroll
    for (int t8 = 0; t8 < 8; ++t8) acc[t8] = zero;

#pragma unroll
    for (int t8 = 0; t8 < 8; ++t8) {
        const short* brow = lds_w + (t8 * 16 + m) * LDA + quad * 8;  // W^T[n][k], n = t8*16+m
#pragma unroll
        for (int k0 = 0; k0 < 4; ++k0) {
            bf16x8 bf = *(const bf16x8*)(brow + k0 * 32);
            acc[t8] = __builtin_amdgcn_mfma_f32_16x16x32_bf16(af[k0], bf, acc[t8], 0, 0, 0);
        }
    }

    __syncthreads();   // all A-frag ds_reads done; safe to reuse lds_a
    // C/D layout: col = lane&15, row = quad*4 + reg
#pragma unroll
    for (int t8 = 0; t8 < 8; ++t8) {
#pragma unroll
        for (int r = 0; r < 4; ++r) {
            int row = wv * 16 + quad * 4 + r;
            int col = t8 * 16 + m;
            lds_a[row * LDA + col] = f2bf(acc[t8][r]);
        }
    }
    __syncthreads();
    // coalesced store: 64 rows x 16 uint4
#pragma unroll
    for (int i = 0; i < 4; ++i) {
        int f4 = tid + i * 256;               // 0..1023
        int row = f4 >> 4, g = f4 & 15;
        if (row0 + row < nrows) {
            uint4 u = *(const uint4*)(lds_a + row * LDA + g * 8);
            *(uint4*)((char*)Y + (size_t)(row0 + row) * 256 + g * 16) = u;
        }
    }
}

// ---------------- segment gather-sum (bf16 tables, f32 accumulate) ----------------
// one 64-lane wave per segment; lane owns features {2*lane, 2*lane+1}; 8 rows in flight
__device__ __forceinline__ void seg_sum_bf2(const __hip_bfloat162* __restrict__ src,
                                            const int* __restrict__ col,
                                            int s, int e, int lane,
                                            float& ax, float& ay) {
    ax = 0.f; ay = 0.f;
    for (int base = s; base < e; base += 64) {
        int j = base + lane;
        int myidx = (j < e) ? col[j] : 0;
        int cnt = e - base; if (cnt > 64) cnt = 64;
        int m = 0;
        for (; m + 8 <= cnt; m += 8) {
            int i0 = __shfl(myidx, m);
            int i1 = __shfl(myidx, m + 1);
            int i2 = __shfl(myidx, m + 2);
            int i3 = __shfl(myidx, m + 3);
            int i4 = __shfl(myidx, m + 4);
            int i5 = __shfl(myidx, m + 5);
            int i6 = __shfl(myidx, m + 6);
            int i7 = __shfl(myidx, m + 7);
            float2 v0 = __bfloat1622float2(src[(size_t)i0 * 64 + lane]);
            float2 v1 = __bfloat1622float2(src[(size_t)i1 * 64 + lane]);
            float2 v2 = __bfloat1622float2(src[(size_t)i2 * 64 + lane]);
            float2 v3 = __bfloat1622float2(src[(size_t)i3 * 64 + lane]);
            float2 v4 = __bfloat1622float2(src[(size_t)i4 * 64 + lane]);
            float2 v5 = __bfloat1622float2(src[(size_t)i5 * 64 + lane]);
            float2 v6 = __bfloat1622float2(src[(size_t)i6 * 64 + lane]);
            float2 v7 = __bfloat1622float2(src[(size_t)i7 * 64 + lane]);
            ax += ((v0.x + v1.x) + (v2.x + v3.x)) + ((v4.x + v5.x) + (v6.x + v7.x));
            ay += ((v0.y + v1.y) + (v2.y + v3.y)) + ((v4.y + v5.y) + (v6.y + v7.y));
        }
        for (; m + 2 <= cnt; m += 2) {
            int i0 = __shfl(myidx, m);
            int i1 = __shfl(myidx, m + 1);
            float2 v0 = __bfloat1622float2(src[(size_t)i0 * 64 + lane]);
            float2 v1 = __bfloat1622float2(src[(size_t)i1 * 64 + lane]);
            ax += v0.x + v1.x;
            ay += v0.y + v1.y;
        }
        if (m < cnt) {
            int i0 = __shfl(myidx, m);
            float2 v = __bfloat1622float2(src[(size_t)i0 * 64 + lane]);
            ax += v.x; ay += v.y;
        }
    }
}

// e[h] = Binv[h] * sum_{nodes in h} src[node]     (bf16 out)
__launch_bounds__(256)
__global__ void edge_agg_kernel(const __hip_bfloat162* __restrict__ src,
                                const int* __restrict__ seg_start, const int* __restrict__ seg_cnt,
                                const int* __restrict__ col, const float* __restrict__ scale,
                                __hip_bfloat162* __restrict__ dst) {
    int wid = threadIdx.x >> 6, lane = threadIdx.x & 63;
    int seg = blockIdx.x * 4 + wid;
    int s = seg_start[seg], e = s + seg_cnt[seg];
    float ax, ay;
    seg_sum_bf2(src, col, s, e, lane, ax, ay);
    float sc = scale[seg];
    dst[(size_t)seg * 64 + lane] = __float22bfloat162_rn(make_float2(ax * sc, ay * sc));
}

// out[n] = relu(Dinv[n] * sum + bias)   (bf16 out)
__launch_bounds__(256)
__global__ void node_agg_relu_kernel(const __hip_bfloat162* __restrict__ src,
                                     const int* __restrict__ seg_start, const int* __restrict__ seg_cnt,
                                     const int* __restrict__ col, const float* __restrict__ scale,
                                     const float* __restrict__ bias,
                                     __hip_bfloat162* __restrict__ dst) {
    int wid = threadIdx.x >> 6, lane = threadIdx.x & 63;
    int seg = blockIdx.x * 4 + wid;
    int s = seg_start[seg], e = s + seg_cnt[seg];
    float ax, ay;
    seg_sum_bf2(src, col, s, e, lane, ax, ay);
    float sc = scale[seg];
    float2 b = *(const float2*)(bias + lane * 2);
    float ox = fmaxf(ax * sc + b.x, 0.f);
    float oy = fmaxf(ay * sc + b.y, 0.f);
    dst[(size_t)seg * 64 + lane] = __float22bfloat162_rn(make_float2(ox, oy));
}

// final layer: relu node output -> per-block partial column sums (f32)
__launch_bounds__(256)
__global__ void node_agg_final_kernel(const __hip_bfloat162* __restrict__ src,
                                      const int* __restrict__ seg_start, const int* __restrict__ seg_cnt,
                                      const int* __restrict__ col, const float* __restrict__ scale,
                                      const float* __restrict__ bias,
                                      float* __restrict__ partials) {
    __shared__ float sd[4 * 128];
    int wid = threadIdx.x >> 6, lane = threadIdx.x & 63;
    int seg = blockIdx.x * 4 + wid;
    int s = seg_start[seg], e = s + seg_cnt[seg];
    float ax, ay;
    seg_sum_bf2(src, col, s, e, lane, ax, ay);
    float sc = scale[seg];
    float2 b = *(const float2*)(bias + lane * 2);
    sd[wid * 128 + lane * 2]     = fmaxf(ax * sc + b.x, 0.f);
    sd[wid * 128 + lane * 2 + 1] = fmaxf(ay * sc + b.y, 0.f);
    __syncthreads();
    int t = threadIdx.x;
    if (t < 128) {
        partials[(size_t)blockIdx.x * 128 + t] =
            sd[t] + sd[128 + t] + sd[256 + t] + sd[384 + t];
    }
}

__global__ void mean_reduce_kernel(const float* __restrict__ partials, float* __restrict__ out,
                                   int nblocks) {
    __shared__ float sd[256];
    int c = blockIdx.x;
    float acc = 0.f;
    for (int i = threadIdx.x; i < nblocks; i += 256)
        acc += partials[(size_t)i * 128 + c];
    sd[threadIdx.x] = acc;
    __syncthreads();
    for (int off = 128; off > 0; off >>= 1) {
        if ((int)threadIdx.x < off) sd[threadIdx.x] += sd[threadIdx.x + off];
        __syncthreads();
    }
    if (threadIdx.x == 0) out[c] = sd[0] * (1.0f / (float)N_NODES);
}

// ---------------- launch ----------------
extern "C" void kernel_launch(void* const* d_in, const int* in_sizes, int n_in,
                              void* d_out, int out_size, void* d_ws, size_t ws_size,
                              hipStream_t stream) {
    const float* x  = (const float*)d_in[0];
    const int*   ei = (const int*)d_in[1];
    const float* w1 = (const float*)d_in[2];
    const float* b1 = (const float*)d_in[3];
    const float* w2 = (const float*)d_in[4];
    const float* b2 = (const float*)d_in[5];
    float* out = (float*)d_out;
    const int* nidx = ei;
    const int* hidx = ei + N_INC;

    char* wsp = (char*)d_ws;
    size_t off = 0;
    auto alloc = [&](size_t bytes) -> void* {
        void* p = wsp + off;
        off += (bytes + 255) & ~(size_t)255;
        return p;
    };

    __hip_bfloat162* B0 = (__hip_bfloat162*)alloc((size_t)N_NODES * 128 * 2);
    __hip_bfloat162* B1 = (__hip_bfloat162*)alloc((size_t)N_NODES * 128 * 2);
    unsigned* bin_e  = (unsigned*)alloc((size_t)NBUCK * CAP * 4);
    unsigned* bin_n  = (unsigned*)alloc((size_t)NBUCK * CAP * 4);
    int* csr_e       = (int*)alloc((size_t)NBUCK * CAP * 4);
    int* csr_n       = (int*)alloc((size_t)NBUCK * CAP * 4);
    float* partials  = (float*)alloc((size_t)(N_NODES / 4) * 128 * 4);
    int* segs_e      = (int*)alloc((size_t)N_NODES * 4);
    int* segc_e      = (int*)alloc((size_t)N_NODES * 4);
    int* segs_n      = (int*)alloc((size_t)N_NODES * 4);
    int* segc_n      = (int*)alloc((size_t)N_NODES * 4);
    float* scale_e   = (float*)alloc((size_t)N_NODES * 4);
    float* scale_n   = (float*)alloc((size_t)N_NODES * 4);
    // contiguous counter block so one memset covers both (round-2 bug fix)
    int* gcnt        = (int*)alloc((size_t)2 * NBUCK * 4);
    int* gcnt_e = gcnt;
    int* gcnt_n = gcnt + NBUCK;

    hipMemsetAsync(gcnt, 0, (size_t)2 * NBUCK * sizeof(int), stream);

    binA_kernel<<<NBLKA, 256, 0, stream>>>(nidx, hidx, gcnt_e, gcnt_n, bin_e, bin_n);
    binB_kernel<<<NBUCK, 512, 0, stream>>>(gcnt_e, bin_e, csr_e, segs_e, segc_e, scale_e);
    binB_kernel<<<NBUCK, 512, 0, stream>>>(gcnt_n, bin_n, csr_n, segs_n, segc_n, scale_n);

    int gGemm = (N_NODES + 63) / 64;
    int gSeg = N_NODES / 4;

    // layer 1
    gemm_mfma_kernel<float><<<gGemm, 256, 0, stream>>>(x, w1, (__hip_bfloat16*)B0, N_NODES);
    edge_agg_kernel<<<gSeg, 256, 0, stream>>>(B0, segs_e, segc_e, csr_e, scale_e, B1);
    node_agg_relu_kernel<<<gSeg, 256, 0, stream>>>(B1, segs_n, segc_n, csr_n, scale_n, b1, B0);
    // layer 2
    gemm_mfma_kernel<__hip_bfloat16><<<gGemm, 256, 0, stream>>>((const __hip_bfloat16*)B0, w2,
                                                                (__hip_bfloat16*)B1, N_NODES);
    edge_agg_kernel<<<gSeg, 256, 0, stream>>>(B1, segs_e, segc_e, csr_e, scale_e, B0);
    node_agg_final_kernel<<<gSeg, 256, 0, stream>>>(B0, segs_n, segc_n, csr_n, scale_n, b2, partials);
    mean_reduce_kernel<<<128, 256, 0, stream>>>(partials, out, N_NODES / 4);
}

// Round 5
// 495.702 us; speedup vs baseline: 2.1262x; 1.0120x over previous
//
#include <hip/hip_runtime.h>
#include <hip/hip_bf16.h>

#define N_NODES 100000
#define N_HEDGES 100000
#define N_INC 1600000
#define D 128

#define B_KEYS 512            // keys per bucket
#define NBUCK 196             // ceil(100000/512)
#define CAP 10240             // bucket capacity (mean 8192, sigma ~90)
#define NBLKA 200
#define CHUNK (N_INC / NBLKA) // 8000

#define LDA 136               // padded bf16 row stride for GEMM LDS tiles

typedef __attribute__((ext_vector_type(8))) short bf16x8;
typedef __attribute__((ext_vector_type(4))) float f32x4;

__device__ __forceinline__ short f2bf(float v) {
    __hip_bfloat16 b = __float2bfloat16(v);
    return *(short*)&b;
}
__device__ __forceinline__ unsigned packbf2(float x, float y) {
    __hip_bfloat162 p = __float22bfloat162_rn(make_float2(x, y));
    return *(unsigned*)&p;
}

// ---------------- Phase A: bucket partition both directions ----------------
__launch_bounds__(256)
__global__ void binA_kernel(const int* __restrict__ nidx, const int* __restrict__ hidx,
                            int* __restrict__ gcnt_e, int* __restrict__ gcnt_n,
                            unsigned* __restrict__ bin_e, unsigned* __restrict__ bin_n) {
    __shared__ int hist_e[NBUCK], hist_n[NBUCK], base_e[NBUCK], base_n[NBUCK];
    int t = threadIdx.x;
    for (int b = t; b < NBUCK; b += 256) { hist_e[b] = 0; hist_n[b] = 0; }
    __syncthreads();
    int start = blockIdx.x * CHUNK;
    for (int i = t; i < CHUNK; i += 256) {
        int h = hidx[start + i], n = nidx[start + i];
        atomicAdd(&hist_e[h >> 9], 1);
        atomicAdd(&hist_n[n >> 9], 1);
    }
    __syncthreads();
    for (int b = t; b < NBUCK; b += 256) {
        base_e[b] = atomicAdd(&gcnt_e[b], hist_e[b]);
        base_n[b] = atomicAdd(&gcnt_n[b], hist_n[b]);
        hist_e[b] = 0; hist_n[b] = 0;
    }
    __syncthreads();
    for (int i = t; i < CHUNK; i += 256) {
        int h = hidx[start + i], n = nidx[start + i];
        int be = h >> 9, bn = n >> 9;
        int oe = base_e[be] + atomicAdd(&hist_e[be], 1);
        if (oe >= 0 && oe < CAP) bin_e[(size_t)be * CAP + oe] = ((unsigned)(h & 511) << 17) | (unsigned)n;
        int on = base_n[bn] + atomicAdd(&hist_n[bn], 1);
        if (on >= 0 && on < CAP) bin_n[(size_t)bn * CAP + on] = ((unsigned)(n & 511) << 17) | (unsigned)h;
    }
}

// ---------------- Phase B: per-bucket counting sort -> csr + seg meta ----------------
__launch_bounds__(512)
__global__ void binB_kernel(const int* __restrict__ gcnt, const unsigned* __restrict__ bin,
                            int* __restrict__ csr, int* __restrict__ seg_start,
                            int* __restrict__ seg_cnt, float* __restrict__ scale) {
    __shared__ int kc[B_KEYS];
    __shared__ int ks[B_KEYS];
    int b = blockIdx.x;
    int t = threadIdx.x;
    int cnt = gcnt[b];
    if (cnt > CAP) cnt = CAP;
    kc[t] = 0;
    __syncthreads();
    const unsigned* items = bin + (size_t)b * CAP;
    for (int i = t; i < cnt; i += 512) atomicAdd(&kc[items[i] >> 17], 1);
    __syncthreads();
    ks[t] = kc[t];
    __syncthreads();
    for (int off = 1; off < 512; off <<= 1) {
        int v = (t >= off) ? ks[t - off] : 0;
        __syncthreads();
        ks[t] += v;
        __syncthreads();
    }
    int mycnt = kc[t];
    int sstart = b * CAP + (ks[t] - mycnt);
    int k = b * B_KEYS + t;
    if (k < N_NODES) {
        seg_start[k] = sstart;
        seg_cnt[k] = mycnt;
        scale[k] = mycnt ? 1.0f / (float)mycnt : 0.0f;
    }
    __syncthreads();
    kc[t] = sstart;
    __syncthreads();
    for (int i = t; i < cnt; i += 512) {
        unsigned it = items[i];
        int pos = atomicAdd(&kc[it >> 17], 1);
        csr[pos] = (int)(it & 0x1FFFFu);
    }
}

// ---------------- MFMA bf16 GEMM: Y[nrows,128](bf16) = X[nrows,128] * W[128,128] ----
template <typename T>
__launch_bounds__(256)
__global__ void gemm_mfma_kernel(const T* __restrict__ X, const float* __restrict__ W,
                                 __hip_bfloat16* __restrict__ Y, int nrows) {
    __shared__ short lds_a[64 * LDA];    // A tile, reused for output staging
    __shared__ short lds_w[128 * LDA];   // W^T: [n][k]
    int tid = threadIdx.x;
    int row0 = blockIdx.x * 64;

    // stage W^T: W[k][n] f32 -> lds_w[n*LDA + k]
    {
        const float4* w4 = (const float4*)W;
#pragma unroll
        for (int i = 0; i < 16; ++i) {
            int idx = tid + i * 256;          // k*32 + c4, 0..4095
            int k = idx >> 5;
            int n0 = (idx & 31) * 4;
            float4 v = w4[idx];
            lds_w[(n0 + 0) * LDA + k] = f2bf(v.x);
            lds_w[(n0 + 1) * LDA + k] = f2bf(v.y);
            lds_w[(n0 + 2) * LDA + k] = f2bf(v.z);
            lds_w[(n0 + 3) * LDA + k] = f2bf(v.w);
        }
    }
    // stage A tile as bf16
    if constexpr (sizeof(T) == 4) {
        const float4* xg = (const float4*)X;
#pragma unroll
        for (int i = 0; i < 8; ++i) {
            int f4 = tid + i * 256;           // 64 rows x 32 float4
            int row = f4 >> 5, c4 = f4 & 31;
            float4 v = make_float4(0.f, 0.f, 0.f, 0.f);
            if (row0 + row < nrows) v = xg[(size_t)(row0 + row) * 32 + c4];
            short* d = lds_a + row * LDA + c4 * 4;
            d[0] = f2bf(v.x); d[1] = f2bf(v.y); d[2] = f2bf(v.z); d[3] = f2bf(v.w);
        }
    } else {
#pragma unroll
        for (int i = 0; i < 4; ++i) {
            int c = tid + i * 256;            // 64 rows x 16 uint4
            int row = c >> 4, g = c & 15;
            uint4 u = make_uint4(0, 0, 0, 0);
            if (row0 + row < nrows) u = *(const uint4*)((const char*)X + (size_t)(row0 + row) * 256 + g * 16);
            *(uint4*)(lds_a + row * LDA + g * 8) = u;
        }
    }
    __syncthreads();

    int wv = tid >> 6, lane = tid & 63;
    int m = lane & 15, quad = lane >> 4;

    // A fragments: A[m][k = k0 + quad*8 + j]
    const short* arow = lds_a + (wv * 16 + m) * LDA + quad * 8;
    bf16x8 af[4];
#pragma unroll
    for (int k0 = 0; k0 < 4; ++k0) af[k0] = *(const bf16x8*)(arow + k0 * 32);

    f32x4 zero = {0.f, 0.f, 0.f, 0.f};
    f32x4 acc[8];
#pragma unroll
    for (int t8 = 0; t8 < 8; ++t8) acc[t8] = zero;

#pragma unroll
    for (int t8 = 0; t8 < 8; ++t8) {
        const short* brow = lds_w + (t8 * 16 + m) * LDA + quad * 8;  // W^T[n][k], n = t8*16+m
#pragma unroll
        for (int k0 = 0; k0 < 4; ++k0) {
            bf16x8 bf = *(const bf16x8*)(brow + k0 * 32);
            acc[t8] = __builtin_amdgcn_mfma_f32_16x16x32_bf16(af[k0], bf, acc[t8], 0, 0, 0);
        }
    }

    __syncthreads();   // all A-frag ds_reads done; safe to reuse lds_a
    // C/D layout: col = lane&15, row = quad*4 + reg
#pragma unroll
    for (int t8 = 0; t8 < 8; ++t8) {
#pragma unroll
        for (int r = 0; r < 4; ++r) {
            int row = wv * 16 + quad * 4 + r;
            int col = t8 * 16 + m;
            lds_a[row * LDA + col] = f2bf(acc[t8][r]);
        }
    }
    __syncthreads();
    // coalesced store: 64 rows x 16 uint4
#pragma unroll
    for (int i = 0; i < 4; ++i) {
        int f4 = tid + i * 256;               // 0..1023
        int row = f4 >> 4, g = f4 & 15;
        if (row0 + row < nrows) {
            uint4 u = *(const uint4*)(lds_a + row * LDA + g * 8);
            *(uint4*)((char*)Y + (size_t)(row0 + row) * 256 + g * 16) = u;
        }
    }
}

// ---------------- segment gather-sum: 4 rows per vmem instruction ----------------
// lane = sub(row slot, lane>>4) x fl(feature group, lane&15); lane loads 16 B = 8 bf16.
// One dwordx4 gather fetches 4 rows (1 KiB). acc[8] = features fl*8 .. fl*8+7.
__device__ __forceinline__ void acc8_add(float* a, uint4 u) {
    a[0] += __uint_as_float(u.x << 16); a[1] += __uint_as_float(u.x & 0xFFFF0000u);
    a[2] += __uint_as_float(u.y << 16); a[3] += __uint_as_float(u.y & 0xFFFF0000u);
    a[4] += __uint_as_float(u.z << 16); a[5] += __uint_as_float(u.z & 0xFFFF0000u);
    a[6] += __uint_as_float(u.w << 16); a[7] += __uint_as_float(u.w & 0xFFFF0000u);
}
__device__ __forceinline__ void acc8_fma(float* a, uint4 u, float msk) {
    a[0] = fmaf(msk, __uint_as_float(u.x << 16), a[0]);
    a[1] = fmaf(msk, __uint_as_float(u.x & 0xFFFF0000u), a[1]);
    a[2] = fmaf(msk, __uint_as_float(u.y << 16), a[2]);
    a[3] = fmaf(msk, __uint_as_float(u.y & 0xFFFF0000u), a[3]);
    a[4] = fmaf(msk, __uint_as_float(u.z << 16), a[4]);
    a[5] = fmaf(msk, __uint_as_float(u.z & 0xFFFF0000u), a[5]);
    a[6] = fmaf(msk, __uint_as_float(u.w << 16), a[6]);
    a[7] = fmaf(msk, __uint_as_float(u.w & 0xFFFF0000u), a[7]);
}

__device__ __forceinline__ void seg_sum_rows(const char* __restrict__ src,
                                             const int* __restrict__ col,
                                             int s, int e, int lane, float* acc) {
    int fl = lane & 15, sub = lane >> 4;
    for (int base = s; base < e; base += 64) {
        int j = base + lane;
        int myidx = (j < e) ? col[j] : 0;
        int cnt = e - base; if (cnt > 64) cnt = 64;
        int cnt4 = cnt & ~3;
        int m = 0;
        for (; m + 8 <= cnt4; m += 8) {           // 2 loads in flight
            int ia = __shfl(myidx, m + sub);
            int ib = __shfl(myidx, m + 4 + sub);
            uint4 ua = *(const uint4*)(src + (size_t)ia * 256 + fl * 16);
            uint4 ub = *(const uint4*)(src + (size_t)ib * 256 + fl * 16);
            acc8_add(acc, ua);
            acc8_add(acc, ub);
        }
        for (; m < cnt4; m += 4) {
            int ia = __shfl(myidx, m + sub);
            uint4 ua = *(const uint4*)(src + (size_t)ia * 256 + fl * 16);
            acc8_add(acc, ua);
        }
        if (m < cnt) {                            // masked tail batch
            int sl = m + sub;
            int slc = sl < cnt ? sl : cnt - 1;
            float msk = sl < cnt ? 1.0f : 0.0f;
            int ia = __shfl(myidx, slc);
            uint4 ua = *(const uint4*)(src + (size_t)ia * 256 + fl * 16);
            acc8_fma(acc, ua, msk);
        }
    }
}

__device__ __forceinline__ void cross_reduce8(float* a) {
#pragma unroll
    for (int i = 0; i < 8; ++i) {
        a[i] += __shfl_xor(a[i], 16);
        a[i] += __shfl_xor(a[i], 32);
    }
}

// e[h] = Binv[h] * sum_{nodes in h} src[node]     (bf16 out)
__launch_bounds__(256)
__global__ void edge_agg_kernel(const char* __restrict__ src,
                                const int* __restrict__ seg_start, const int* __restrict__ seg_cnt,
                                const int* __restrict__ col, const float* __restrict__ scale,
                                char* __restrict__ dst) {
    int wid = threadIdx.x >> 6, lane = threadIdx.x & 63;
    int seg = blockIdx.x * 4 + wid;
    int s = seg_start[seg], e = s + seg_cnt[seg];
    float acc[8] = {0.f, 0.f, 0.f, 0.f, 0.f, 0.f, 0.f, 0.f};
    seg_sum_rows(src, col, s, e, lane, acc);
    cross_reduce8(acc);
    if ((lane >> 4) == 0) {
        int fl = lane & 15;
        float sc = scale[seg];
        uint4 o;
        o.x = packbf2(acc[0] * sc, acc[1] * sc);
        o.y = packbf2(acc[2] * sc, acc[3] * sc);
        o.z = packbf2(acc[4] * sc, acc[5] * sc);
        o.w = packbf2(acc[6] * sc, acc[7] * sc);
        *(uint4*)(dst + (size_t)seg * 256 + fl * 16) = o;
    }
}

// out[n] = relu(Dinv[n] * sum + bias)   (bf16 out)
__launch_bounds__(256)
__global__ void node_agg_relu_kernel(const char* __restrict__ src,
                                     const int* __restrict__ seg_start, const int* __restrict__ seg_cnt,
                                     const int* __restrict__ col, const float* __restrict__ scale,
                                     const float* __restrict__ bias,
                                     char* __restrict__ dst) {
    int wid = threadIdx.x >> 6, lane = threadIdx.x & 63;
    int seg = blockIdx.x * 4 + wid;
    int s = seg_start[seg], e = s + seg_cnt[seg];
    float acc[8] = {0.f, 0.f, 0.f, 0.f, 0.f, 0.f, 0.f, 0.f};
    seg_sum_rows(src, col, s, e, lane, acc);
    cross_reduce8(acc);
    if ((lane >> 4) == 0) {
        int fl = lane & 15;
        float sc = scale[seg];
        const float4* b4 = (const float4*)(bias + fl * 8);
        float4 blo = b4[0], bhi = b4[1];
        uint4 o;
        o.x = packbf2(fmaxf(acc[0] * sc + blo.x, 0.f), fmaxf(acc[1] * sc + blo.y, 0.f));
        o.y = packbf2(fmaxf(acc[2] * sc + blo.z, 0.f), fmaxf(acc[3] * sc + blo.w, 0.f));
        o.z = packbf2(fmaxf(acc[4] * sc + bhi.x, 0.f), fmaxf(acc[5] * sc + bhi.y, 0.f));
        o.w = packbf2(fmaxf(acc[6] * sc + bhi.z, 0.f), fmaxf(acc[7] * sc + bhi.w, 0.f));
        *(uint4*)(dst + (size_t)seg * 256 + fl * 16) = o;
    }
}

// final layer: relu node output -> per-block partial column sums (f32)
__launch_bounds__(256)
__global__ void node_agg_final_kernel(const char* __restrict__ src,
                                      const int* __restrict__ seg_start, const int* __restrict__ seg_cnt,
                                      const int* __restrict__ col, const float* __restrict__ scale,
                                      const float* __restrict__ bias,
                                      float* __restrict__ partials) {
    __shared__ __align__(16) float sd[4 * 128];
    int wid = threadIdx.x >> 6, lane = threadIdx.x & 63;
    int seg = blockIdx.x * 4 + wid;
    int s = seg_start[seg], e = s + seg_cnt[seg];
    float acc[8] = {0.f, 0.f, 0.f, 0.f, 0.f, 0.f, 0.f, 0.f};
    seg_sum_rows(src, col, s, e, lane, acc);
    cross_reduce8(acc);
    if ((lane >> 4) == 0) {
        int fl = lane & 15;
        float sc = scale[seg];
        const float4* b4 = (const float4*)(bias + fl * 8);
        float4 blo = b4[0], bhi = b4[1];
        float4* d = (float4*)(sd + wid * 128 + fl * 8);
        d[0] = make_float4(fmaxf(acc[0] * sc + blo.x, 0.f), fmaxf(acc[1] * sc + blo.y, 0.f),
                           fmaxf(acc[2] * sc + blo.z, 0.f), fmaxf(acc[3] * sc + blo.w, 0.f));
        d[1] = make_float4(fmaxf(acc[4] * sc + bhi.x, 0.f), fmaxf(acc[5] * sc + bhi.y, 0.f),
                           fmaxf(acc[6] * sc + bhi.z, 0.f), fmaxf(acc[7] * sc + bhi.w, 0.f));
    }
    __syncthreads();
    int t = threadIdx.x;
    if (t < 128) {
        partials[(size_t)blockIdx.x * 128 + t] =
            sd[t] + sd[128 + t] + sd[256 + t] + sd[384 + t];
    }
}

__global__ void mean_reduce_kernel(const float* __restrict__ partials, float* __restrict__ out,
                                   int nblocks) {
    __shared__ float sd[256];
    int c = blockIdx.x;
    float acc = 0.f;
    for (int i = threadIdx.x; i < nblocks; i += 256)
        acc += partials[(size_t)i * 128 + c];
    sd[threadIdx.x] = acc;
    __syncthreads();
    for (int off = 128; off > 0; off >>= 1) {
        if ((int)threadIdx.x < off) sd[threadIdx.x] += sd[threadIdx.x + off];
        __syncthreads();
    }
    if (threadIdx.x == 0) out[c] = sd[0] * (1.0f / (float)N_NODES);
}

// ---------------- launch ----------------
extern "C" void kernel_launch(void* const* d_in, const int* in_sizes, int n_in,
                              void* d_out, int out_size, void* d_ws, size_t ws_size,
                              hipStream_t stream) {
    const float* x  = (const float*)d_in[0];
    const int*   ei = (const int*)d_in[1];
    const float* w1 = (const float*)d_in[2];
    const float* b1 = (const float*)d_in[3];
    const float* w2 = (const float*)d_in[4];
    const float* b2 = (const float*)d_in[5];
    float* out = (float*)d_out;
    const int* nidx = ei;
    const int* hidx = ei + N_INC;

    char* wsp = (char*)d_ws;
    size_t off = 0;
    auto alloc = [&](size_t bytes) -> void* {
        void* p = wsp + off;
        off += (bytes + 255) & ~(size_t)255;
        return p;
    };

    char* B0         = (char*)alloc((size_t)N_NODES * 128 * 2);
    char* B1         = (char*)alloc((size_t)N_NODES * 128 * 2);
    unsigned* bin_e  = (unsigned*)alloc((size_t)NBUCK * CAP * 4);
    unsigned* bin_n  = (unsigned*)alloc((size_t)NBUCK * CAP * 4);
    int* csr_e       = (int*)alloc((size_t)NBUCK * CAP * 4);
    int* csr_n       = (int*)alloc((size_t)NBUCK * CAP * 4);
    float* partials  = (float*)alloc((size_t)(N_NODES / 4) * 128 * 4);
    int* segs_e      = (int*)alloc((size_t)N_NODES * 4);
    int* segc_e      = (int*)alloc((size_t)N_NODES * 4);
    int* segs_n      = (int*)alloc((size_t)N_NODES * 4);
    int* segc_n      = (int*)alloc((size_t)N_NODES * 4);
    float* scale_e   = (float*)alloc((size_t)N_NODES * 4);
    float* scale_n   = (float*)alloc((size_t)N_NODES * 4);
    // contiguous counter block so one memset covers both (round-2 bug fix)
    int* gcnt        = (int*)alloc((size_t)2 * NBUCK * 4);
    int* gcnt_e = gcnt;
    int* gcnt_n = gcnt + NBUCK;

    hipMemsetAsync(gcnt, 0, (size_t)2 * NBUCK * sizeof(int), stream);

    binA_kernel<<<NBLKA, 256, 0, stream>>>(nidx, hidx, gcnt_e, gcnt_n, bin_e, bin_n);
    binB_kernel<<<NBUCK, 512, 0, stream>>>(gcnt_e, bin_e, csr_e, segs_e, segc_e, scale_e);
    binB_kernel<<<NBUCK, 512, 0, stream>>>(gcnt_n, bin_n, csr_n, segs_n, segc_n, scale_n);

    int gGemm = (N_NODES + 63) / 64;
    int gSeg = N_NODES / 4;

    // layer 1
    gemm_mfma_kernel<float><<<gGemm, 256, 0, stream>>>(x, w1, (__hip_bfloat16*)B0, N_NODES);
    edge_agg_kernel<<<gSeg, 256, 0, stream>>>(B0, segs_e, segc_e, csr_e, scale_e, B1);
    node_agg_relu_kernel<<<gSeg, 256, 0, stream>>>(B1, segs_n, segc_n, csr_n, scale_n, b1, B0);
    // layer 2
    gemm_mfma_kernel<__hip_bfloat16><<<gGemm, 256, 0, stream>>>((const __hip_bfloat16*)B0, w2,
                                                                (__hip_bfloat16*)B1, N_NODES);
    edge_agg_kernel<<<gSeg, 256, 0, stream>>>(B1, segs_e, segc_e, csr_e, scale_e, B0);
    node_agg_final_kernel<<<gSeg, 256, 0, stream>>>(B0, segs_n, segc_n, csr_n, scale_n, b2, partials);
    mean_reduce_kernel<<<128, 256, 0, stream>>>(partials, out, N_NODES / 4);
}